// Round 5
// baseline (144.684 us; speedup 1.0000x reference)
//
#include <hip/hip_runtime.h>
#include <math.h>

// CapsuleLayer dynamic routing, fused. R5: MB=2 batches per block, in-thread.
// Each W float4 load feeds BOTH batches' accumulators (register reuse) ->
// W L2 traffic halves (755 MB, ~22 us floor). pri0[9]+pri1[9] = 72 VGPRs;
// demand ~110. VGPR budget engineered via LDS: x[b0],x[b1] staging (72 KB,
// OVERLAID with phase-B logits - x dead after Phase A) pushes LDS to ~75 KB
// -> 2 blocks/CU -> backend targets 4 waves/EU -> 128-VGPR cap >= demand.
// (R2/R3 lesson: small LDS -> 8 waves/EU target -> 64-cap -> pri spills.)
// c-major blocks: 128 consecutive blocks share W[c] in L2.

#define NBATCH 256
#define NC 10
#define NR 1152
#define IC 8
#define OC 16
#define NITER 3
#define T 512
#define MB 2
#define RPT 9    // NR / 128 r-values per thread per batch

__device__ __forceinline__ float wave_sum(float v) {
#pragma unroll
    for (int m = 1; m <= 32; m <<= 1) v += __shfl_xor(v, m, 64);
    return v;
}
__device__ __forceinline__ float wave_max(float v) {
#pragma unroll
    for (int m = 1; m <= 32; m <<= 1) v = fmaxf(v, __shfl_xor(v, m, 64));
    return v;
}

__global__ __launch_bounds__(T) void caps_route(
    const float* __restrict__ x,   // [B, NR, IC]
    const float* __restrict__ W,   // [NC, NR, IC, OC]
    float* __restrict__ out)       // [B, NC, OC]
{
    // Overlay: Phase A = x[b0]||x[b1] as float4[4608] (73728 B);
    // Phase B = logit0[NR] || logit1[NR] (9216 B of the same region).
    __shared__ float smem[NR * 16];
    __shared__ float red[2 * 128]; // per-batch: 8 waves x 16 outputs
    __shared__ float vout[2 * OC];

    const int t    = threadIdx.x;
    const int og   = t & 3;        // o-quad (o = og*4+j)
    const int rr   = t >> 2;       // 0..127
    const int lane = t & 63;
    const int wid  = t >> 6;       // 0..7

    const int c  = blockIdx.x >> 7;     // c-major: 128 consecutive blocks share W[c]
    const int bp = blockIdx.x & 127;
    const int b0 = bp * 2;              // b1 = b0+1, x rows contiguous

    // ---------------- stage x[b0],x[b1] into LDS (one contiguous copy) -----
    float4* xs4 = (float4*)smem;
    const float4* __restrict__ xg = (const float4*)(x + (size_t)b0 * (NR * IC));
    for (int k = t; k < NR * 4; k += T) xs4[k] = xg[k];
    __syncthreads();

    // ---------------- Phase A: pri{0,1}[p] for r=rr+128p, o-quad og --------
    float4 pri0[RPT], pri1[RPT];
    const float4* __restrict__ wb = (const float4*)(W + (size_t)c * (NR * IC * OC));
    const float4* xb0 = xs4;
    const float4* xb1 = xs4 + NR * 2;
#pragma unroll
    for (int p = 0; p < RPT; ++p) {
        const int r = rr + (p << 7);
        float4 xa0 = xb0[2 * r], xc0 = xb0[2 * r + 1];
        float4 xa1 = xb1[2 * r], xc1 = xb1[2 * r + 1];
        float xv0[8] = {xa0.x, xa0.y, xa0.z, xa0.w, xc0.x, xc0.y, xc0.z, xc0.w};
        float xv1[8] = {xa1.x, xa1.y, xa1.z, xa1.w, xc1.x, xc1.y, xc1.z, xc1.w};
        const float4* wp = wb + (size_t)r * 32 + og; // float4 idx (r*8+i)*4+og
        float4 a0 = make_float4(0.f, 0.f, 0.f, 0.f);
        float4 a1 = make_float4(0.f, 0.f, 0.f, 0.f);
#pragma unroll
        for (int i = 0; i < 8; ++i) {
            float4 w = wp[i * 4];                    // one load, two batches
            a0.x = fmaf(xv0[i], w.x, a0.x); a1.x = fmaf(xv1[i], w.x, a1.x);
            a0.y = fmaf(xv0[i], w.y, a0.y); a1.y = fmaf(xv1[i], w.y, a1.y);
            a0.z = fmaf(xv0[i], w.z, a0.z); a1.z = fmaf(xv1[i], w.z, a1.z);
            a0.w = fmaf(xv0[i], w.w, a0.w); a1.w = fmaf(xv1[i], w.w, a1.w);
        }
        pri0[p] = a0;
        pri1[p] = a1;
    }
    // NOTE: no barrier here; first logit write (it=0 delta) is 2 barriers
    // below, so all xs4 reads have drained before the overlay is clobbered.
    float* logit0 = smem;        // overlay begins life at it=0 delta update
    float* logit1 = smem + NR;

    // ---------------- Phase B: 3 routing iterations -------------------------
    for (int it = 0; it < NITER; ++it) {
        const bool uni = (it == 0);  // softmax of zeros = uniform
        float m0 = 0.f, m1 = 0.f, invd0 = 0.f, invd1 = 0.f;
        if (!uni) {
            float lm0 = -3.4e38f, lm1 = -3.4e38f;
#pragma unroll
            for (int k = 0; k < 3; ++k) {
                int r = t + (k << 9);
                if (r < NR) {
                    lm0 = fmaxf(lm0, logit0[r]);
                    lm1 = fmaxf(lm1, logit1[r]);
                }
            }
            lm0 = wave_max(lm0); lm1 = wave_max(lm1);
            if (lane == 0) { red[wid] = lm0; red[16 + wid] = lm1; }
            __syncthreads();
            m0 = red[0]; m1 = red[16];
#pragma unroll
            for (int w = 1; w < 8; ++w) {
                m0 = fmaxf(m0, red[w]); m1 = fmaxf(m1, red[16 + w]);
            }
            float ls0 = 0.f, ls1 = 0.f;
#pragma unroll
            for (int k = 0; k < 3; ++k) {
                int r = t + (k << 9);
                if (r < NR) {
                    ls0 += __expf(logit0[r] - m0);
                    ls1 += __expf(logit1[r] - m1);
                }
            }
            ls0 = wave_sum(ls0); ls1 = wave_sum(ls1);
            __syncthreads();             // m reads done before red rewrite
            if (lane == 0) { red[wid] = ls0; red[16 + wid] = ls1; }
            __syncthreads();
            float d0 = red[0], d1 = red[16];
#pragma unroll
            for (int w = 1; w < 8; ++w) { d0 += red[w]; d1 += red[16 + w]; }
            invd0 = 1.f / d0; invd1 = 1.f / d1;
        }

        // s[o] partials, both batches
        float4 s0 = make_float4(0.f, 0.f, 0.f, 0.f);
        float4 s1 = make_float4(0.f, 0.f, 0.f, 0.f);
#pragma unroll
        for (int k = 0; k < RPT; ++k) {
            float w0 = 1.0f, w1 = 1.0f;
            if (!uni) {
                const int r = rr + (k << 7);
                w0 = __expf(logit0[r] - m0);
                w1 = __expf(logit1[r] - m1);
            }
            s0.x = fmaf(w0, pri0[k].x, s0.x); s1.x = fmaf(w1, pri1[k].x, s1.x);
            s0.y = fmaf(w0, pri0[k].y, s0.y); s1.y = fmaf(w1, pri1[k].y, s1.y);
            s0.z = fmaf(w0, pri0[k].z, s0.z); s1.z = fmaf(w1, pri1[k].z, s1.z);
            s0.w = fmaf(w0, pri0[k].w, s0.w); s1.w = fmaf(w1, pri1[k].w, s1.w);
        }
        // reduce over the 16 rr slots (same og) within each wave
#pragma unroll
        for (int msk = 4; msk <= 32; msk <<= 1) {
            s0.x += __shfl_xor(s0.x, msk, 64); s1.x += __shfl_xor(s1.x, msk, 64);
            s0.y += __shfl_xor(s0.y, msk, 64); s1.y += __shfl_xor(s1.y, msk, 64);
            s0.z += __shfl_xor(s0.z, msk, 64); s1.z += __shfl_xor(s1.z, msk, 64);
            s0.w += __shfl_xor(s0.w, msk, 64); s1.w += __shfl_xor(s1.w, msk, 64);
        }
        __syncthreads();                 // stats/prev reads done; also fences
                                         // last xs4 reads at it=0
        if (lane < 4) {
            ((float4*)red)[wid * 4 + og]      = s0; // red[wid*16+o]
            ((float4*)(red + 128))[wid * 4 + og] = s1;
        }
        __syncthreads();

        if (t < 2 * OC) {                // t<16: batch0; 16<=t<32: batch1
            const int bsel = t >> 4, o = t & 15;
            float s = 0.f;
#pragma unroll
            for (int w = 0; w < 8; ++w) s += red[bsel * 128 + w * 16 + o];
            s *= uni ? (1.0f / 1152.0f) : (bsel ? invd1 : invd0);
            float sq = s * s;
#pragma unroll
            for (int msk = 1; msk <= 8; msk <<= 1) sq += __shfl_xor(sq, msk, 64);
            float v = s * (sqrtf(sq) / (1.0f + sq)); // squash
            if (it == NITER - 1) out[((size_t)(b0 + bsel) * NC + c) * OC + o] = v;
            else vout[t] = v;
        }
        __syncthreads();

        if (it < NITER - 1) {
            // logit[r] += sum_o pri[r][o]*v[o]
            float4 v0 = ((const float4*)vout)[og];
            float4 v1 = ((const float4*)(vout + OC))[og];
#pragma unroll
            for (int k = 0; k < RPT; ++k) {
                const int r = rr + (k << 7);
                float d0 = pri0[k].x * v0.x + pri0[k].y * v0.y +
                           pri0[k].z * v0.z + pri0[k].w * v0.w;
                float d1 = pri1[k].x * v1.x + pri1[k].y * v1.y +
                           pri1[k].z * v1.z + pri1[k].w * v1.w;
                d0 += __shfl_xor(d0, 1, 64); d1 += __shfl_xor(d1, 1, 64);
                d0 += __shfl_xor(d0, 2, 64); d1 += __shfl_xor(d1, 2, 64);
                if (og == 0) {
                    if (it == 0) { logit0[r] = d0; logit1[r] = d1; }
                    else         { logit0[r] += d0; logit1[r] += d1; }
                }
            }
            __syncthreads();
        }
    }
}

extern "C" void kernel_launch(void* const* d_in, const int* in_sizes, int n_in,
                              void* d_out, int out_size, void* d_ws, size_t ws_size,
                              hipStream_t stream) {
    const float* x = (const float*)d_in[0];
    const float* W = (const float*)d_in[1];
    float* out = (float*)d_out;
    caps_route<<<dim3(NC * (NBATCH / MB)), dim3(T), 0, stream>>>(x, W, out);
}

// Round 6
// 131.111 us; speedup vs baseline: 1.1035x; 1.1035x over previous
//
#include <hip/hip_runtime.h>
#include <math.h>

// CapsuleLayer dynamic routing, fused. R6 = R5 (MB=2, priors in registers,
// x-staging/logit LDS overlay) + amdgpu_waves_per_eu(4,4).
// R5 diagnosis: latency-bound, concurrency-limited — halving W traffic (MB=2)
// with halved occupancy left dur flat; VGPR_Count=72 (= pri0+pri1 exactly)
// means RA gave minimum registers -> ~2 W loads in flight/wave. LDS (75 KB)
// already pins 2 blocks/CU = 4 waves/EU, so 128 VGPRs are legal; the (4,4)
// clamp tells RA to use them -> Phase A's 72 independent L2 loads get
// software-pipelined ~10 deep. Expect ~4x more loads in flight.

#define NBATCH 256
#define NC 10
#define NR 1152
#define IC 8
#define OC 16
#define NITER 3
#define T 512
#define MB 2
#define RPT 9    // NR / 128 r-values per thread per batch

__device__ __forceinline__ float wave_sum(float v) {
#pragma unroll
    for (int m = 1; m <= 32; m <<= 1) v += __shfl_xor(v, m, 64);
    return v;
}
__device__ __forceinline__ float wave_max(float v) {
#pragma unroll
    for (int m = 1; m <= 32; m <<= 1) v = fmaxf(v, __shfl_xor(v, m, 64));
    return v;
}

__global__ __launch_bounds__(T)
__attribute__((amdgpu_waves_per_eu(4, 4)))   // clamp 4 waves/EU -> 128-VGPR budget
void caps_route(
    const float* __restrict__ x,   // [B, NR, IC]
    const float* __restrict__ W,   // [NC, NR, IC, OC]
    float* __restrict__ out)       // [B, NC, OC]
{
    // Overlay: Phase A = x[b0]||x[b1] as float4[4608] (73728 B);
    // Phase B = logit0[NR] || logit1[NR] (9216 B of the same region).
    __shared__ float smem[NR * 16];
    __shared__ float red[2 * 128]; // per-batch: 8 waves x 16 outputs
    __shared__ float vout[2 * OC];

    const int t    = threadIdx.x;
    const int og   = t & 3;        // o-quad (o = og*4+j)
    const int rr   = t >> 2;       // 0..127
    const int lane = t & 63;
    const int wid  = t >> 6;       // 0..7

    const int c  = blockIdx.x >> 7;     // c-major: 128 consecutive blocks share W[c]
    const int bp = blockIdx.x & 127;
    const int b0 = bp * 2;              // b1 = b0+1, x rows contiguous

    // ---------------- stage x[b0],x[b1] into LDS (one contiguous copy) -----
    float4* xs4 = (float4*)smem;
    const float4* __restrict__ xg = (const float4*)(x + (size_t)b0 * (NR * IC));
    for (int k = t; k < NR * 4; k += T) xs4[k] = xg[k];
    __syncthreads();

    // ---------------- Phase A: pri{0,1}[p] for r=rr+128p, o-quad og --------
    float4 pri0[RPT], pri1[RPT];
    const float4* __restrict__ wb = (const float4*)(W + (size_t)c * (NR * IC * OC));
    const float4* xb0 = xs4;
    const float4* xb1 = xs4 + NR * 2;
#pragma unroll
    for (int p = 0; p < RPT; ++p) {
        const int r = rr + (p << 7);
        float4 xa0 = xb0[2 * r], xc0 = xb0[2 * r + 1];
        float4 xa1 = xb1[2 * r], xc1 = xb1[2 * r + 1];
        float xv0[8] = {xa0.x, xa0.y, xa0.z, xa0.w, xc0.x, xc0.y, xc0.z, xc0.w};
        float xv1[8] = {xa1.x, xa1.y, xa1.z, xa1.w, xc1.x, xc1.y, xc1.z, xc1.w};
        const float4* wp = wb + (size_t)r * 32 + og; // float4 idx (r*8+i)*4+og
        float4 a0 = make_float4(0.f, 0.f, 0.f, 0.f);
        float4 a1 = make_float4(0.f, 0.f, 0.f, 0.f);
#pragma unroll
        for (int i = 0; i < 8; ++i) {
            float4 w = wp[i * 4];                    // one load, two batches
            a0.x = fmaf(xv0[i], w.x, a0.x); a1.x = fmaf(xv1[i], w.x, a1.x);
            a0.y = fmaf(xv0[i], w.y, a0.y); a1.y = fmaf(xv1[i], w.y, a1.y);
            a0.z = fmaf(xv0[i], w.z, a0.z); a1.z = fmaf(xv1[i], w.z, a1.z);
            a0.w = fmaf(xv0[i], w.w, a0.w); a1.w = fmaf(xv1[i], w.w, a1.w);
        }
        pri0[p] = a0;
        pri1[p] = a1;
    }
    // NOTE: no barrier here; first logit write (it=0 delta) is 2 barriers
    // below, so all xs4 reads have drained before the overlay is clobbered.
    float* logit0 = smem;        // overlay begins life at it=0 delta update
    float* logit1 = smem + NR;

    // ---------------- Phase B: 3 routing iterations -------------------------
    for (int it = 0; it < NITER; ++it) {
        const bool uni = (it == 0);  // softmax of zeros = uniform
        float m0 = 0.f, m1 = 0.f, invd0 = 0.f, invd1 = 0.f;
        if (!uni) {
            float lm0 = -3.4e38f, lm1 = -3.4e38f;
#pragma unroll
            for (int k = 0; k < 3; ++k) {
                int r = t + (k << 9);
                if (r < NR) {
                    lm0 = fmaxf(lm0, logit0[r]);
                    lm1 = fmaxf(lm1, logit1[r]);
                }
            }
            lm0 = wave_max(lm0); lm1 = wave_max(lm1);
            if (lane == 0) { red[wid] = lm0; red[16 + wid] = lm1; }
            __syncthreads();
            m0 = red[0]; m1 = red[16];
#pragma unroll
            for (int w = 1; w < 8; ++w) {
                m0 = fmaxf(m0, red[w]); m1 = fmaxf(m1, red[16 + w]);
            }
            float ls0 = 0.f, ls1 = 0.f;
#pragma unroll
            for (int k = 0; k < 3; ++k) {
                int r = t + (k << 9);
                if (r < NR) {
                    ls0 += __expf(logit0[r] - m0);
                    ls1 += __expf(logit1[r] - m1);
                }
            }
            ls0 = wave_sum(ls0); ls1 = wave_sum(ls1);
            __syncthreads();             // m reads done before red rewrite
            if (lane == 0) { red[wid] = ls0; red[16 + wid] = ls1; }
            __syncthreads();
            float d0 = red[0], d1 = red[16];
#pragma unroll
            for (int w = 1; w < 8; ++w) { d0 += red[w]; d1 += red[16 + w]; }
            invd0 = 1.f / d0; invd1 = 1.f / d1;
        }

        // s[o] partials, both batches
        float4 s0 = make_float4(0.f, 0.f, 0.f, 0.f);
        float4 s1 = make_float4(0.f, 0.f, 0.f, 0.f);
#pragma unroll
        for (int k = 0; k < RPT; ++k) {
            float w0 = 1.0f, w1 = 1.0f;
            if (!uni) {
                const int r = rr + (k << 7);
                w0 = __expf(logit0[r] - m0);
                w1 = __expf(logit1[r] - m1);
            }
            s0.x = fmaf(w0, pri0[k].x, s0.x); s1.x = fmaf(w1, pri1[k].x, s1.x);
            s0.y = fmaf(w0, pri0[k].y, s0.y); s1.y = fmaf(w1, pri1[k].y, s1.y);
            s0.z = fmaf(w0, pri0[k].z, s0.z); s1.z = fmaf(w1, pri1[k].z, s1.z);
            s0.w = fmaf(w0, pri0[k].w, s0.w); s1.w = fmaf(w1, pri1[k].w, s1.w);
        }
        // reduce over the 16 rr slots (same og) within each wave
#pragma unroll
        for (int msk = 4; msk <= 32; msk <<= 1) {
            s0.x += __shfl_xor(s0.x, msk, 64); s1.x += __shfl_xor(s1.x, msk, 64);
            s0.y += __shfl_xor(s0.y, msk, 64); s1.y += __shfl_xor(s1.y, msk, 64);
            s0.z += __shfl_xor(s0.z, msk, 64); s1.z += __shfl_xor(s1.z, msk, 64);
            s0.w += __shfl_xor(s0.w, msk, 64); s1.w += __shfl_xor(s1.w, msk, 64);
        }
        __syncthreads();                 // stats/prev reads done; also fences
                                         // last xs4 reads at it=0
        if (lane < 4) {
            ((float4*)red)[wid * 4 + og]         = s0; // red[wid*16+o]
            ((float4*)(red + 128))[wid * 4 + og] = s1;
        }
        __syncthreads();

        if (t < 2 * OC) {                // t<16: batch0; 16<=t<32: batch1
            const int bsel = t >> 4, o = t & 15;
            float s = 0.f;
#pragma unroll
            for (int w = 0; w < 8; ++w) s += red[bsel * 128 + w * 16 + o];
            s *= uni ? (1.0f / 1152.0f) : (bsel ? invd1 : invd0);
            float sq = s * s;
#pragma unroll
            for (int msk = 1; msk <= 8; msk <<= 1) sq += __shfl_xor(sq, msk, 64);
            float v = s * (sqrtf(sq) / (1.0f + sq)); // squash
            if (it == NITER - 1) out[((size_t)(b0 + bsel) * NC + c) * OC + o] = v;
            else vout[t] = v;
        }
        __syncthreads();

        if (it < NITER - 1) {
            // logit[r] += sum_o pri[r][o]*v[o]
            float4 v0 = ((const float4*)vout)[og];
            float4 v1 = ((const float4*)(vout + OC))[og];
#pragma unroll
            for (int k = 0; k < RPT; ++k) {
                const int r = rr + (k << 7);
                float d0 = pri0[k].x * v0.x + pri0[k].y * v0.y +
                           pri0[k].z * v0.z + pri0[k].w * v0.w;
                float d1 = pri1[k].x * v1.x + pri1[k].y * v1.y +
                           pri1[k].z * v1.z + pri1[k].w * v1.w;
                d0 += __shfl_xor(d0, 1, 64); d1 += __shfl_xor(d1, 1, 64);
                d0 += __shfl_xor(d0, 2, 64); d1 += __shfl_xor(d1, 2, 64);
                if (og == 0) {
                    if (it == 0) { logit0[r] = d0; logit1[r] = d1; }
                    else         { logit0[r] += d0; logit1[r] += d1; }
                }
            }
            __syncthreads();
        }
    }
}

extern "C" void kernel_launch(void* const* d_in, const int* in_sizes, int n_in,
                              void* d_out, int out_size, void* d_ws, size_t ws_size,
                              hipStream_t stream) {
    const float* x = (const float*)d_in[0];
    const float* W = (const float*)d_in[1];
    float* out = (float*)d_out;
    caps_route<<<dim3(NC * (NBATCH / MB)), dim3(T), 0, stream>>>(x, W, out);
}